// Round 2
// baseline (37.259 us; speedup 1.0000x reference)
//
#include <hip/hip_runtime.h>
#include <math.h>

#define NVIEWS 4
#define DIM 2048
#define HALFD (DIM / 2)
#define CLAMP_MIN_F 0.0005f
#define CLAMP_MAX_F 0.9995f
#define NORM_EPS_F 1e-12f

// 2 waves per chunk (each wave covers 1024 of the 2048 columns), 4 waves per
// block -> 2 chunks per block, grid = C/2 = 2048 blocks = 32 waves/CU (max
// occupancy). Each wave accumulates the 10 unique dot products over its
// half of D, wave-reduces, and the two halves are combined through LDS.
__global__ __launch_bounds__(256, 8) void chunk_loss_kernel(
    const float* __restrict__ x, float* __restrict__ partials, int C)
{
    const int lane = threadIdx.x & 63;
    const int wave = threadIdx.x >> 6;   // 0..3
    const int lc   = wave >> 1;          // local chunk 0..1
    const int half = wave & 1;           // which half of D
    const int chunk = blockIdx.x * 2 + lc;

    // acc index map: 0:(0,0) 1:(0,1) 2:(0,2) 3:(0,3) 4:(1,1) 5:(1,2)
    //                6:(1,3) 7:(2,2) 8:(2,3) 9:(3,3)
    float acc[10];
#pragma unroll
    for (int p = 0; p < 10; ++p) acc[p] = 0.0f;

    if (chunk < C) {
        const float* base = x + (size_t)chunk * (NVIEWS * DIM) + half * HALFD;
#pragma unroll 2
        for (int it = 0; it < HALFD / 256; ++it) {   // 4 iterations
            const int off = it * 256 + lane * 4;
            float rr[4][4];
#pragma unroll
            for (int i = 0; i < 4; ++i)
                *reinterpret_cast<float4*>(rr[i]) =
                    *reinterpret_cast<const float4*>(base + i * DIM + off);
            int p = 0;
#pragma unroll
            for (int i = 0; i < 4; ++i) {
#pragma unroll
                for (int j = i; j < 4; ++j, ++p) {
#pragma unroll
                    for (int k = 0; k < 4; ++k)
                        acc[p] = fmaf(rr[i][k], rr[j][k], acc[p]);
                }
            }
        }
    }

    // wave-level butterfly reduction across 64 lanes
#pragma unroll
    for (int p = 0; p < 10; ++p) {
#pragma unroll
        for (int s = 32; s > 0; s >>= 1)
            acc[p] += __shfl_xor(acc[p], s, 64);
    }

    __shared__ float lds[4][10];
    if (lane == 0) {
#pragma unroll
        for (int p = 0; p < 10; ++p) lds[wave][p] = acc[p];
    }
    __syncthreads();

    // one lane per chunk combines the two halves and evaluates the loss
    if ((threadIdx.x == 0 || threadIdx.x == 128) && chunk < C) {
        float a[10];
#pragma unroll
        for (int p = 0; p < 10; ++p) a[p] = lds[2 * lc][p] + lds[2 * lc + 1][p];

        const float n0 = fmaxf(sqrtf(a[0]), NORM_EPS_F);
        const float n1 = fmaxf(sqrtf(a[4]), NORM_EPS_F);
        const float n2 = fmaxf(sqrtf(a[7]), NORM_EPS_F);
        const float n3 = fmaxf(sqrtf(a[9]), NORM_EPS_F);
        const float i0 = 1.0f / n0, i1 = 1.0f / n1;
        const float i2 = 1.0f / n2, i3 = 1.0f / n3;
        float sum = 0.0f, s;
#define TERM(P, IA, IB, W)                                    \
        s = a[P] * (IA) * (IB);                               \
        s = fminf(fmaxf(s, CLAMP_MIN_F), CLAMP_MAX_F);        \
        sum += (W) * (-__logf(1.0f - s));
        TERM(0, i0, i0, 1.0f)   // diagonal
        TERM(4, i1, i1, 1.0f)
        TERM(7, i2, i2, 1.0f)
        TERM(9, i3, i3, 1.0f)
        TERM(1, i0, i1, 2.0f)   // off-diagonal pairs, counted twice
        TERM(2, i0, i2, 2.0f)
        TERM(3, i0, i3, 2.0f)
        TERM(5, i1, i2, 2.0f)
        TERM(6, i1, i3, 2.0f)
        TERM(8, i2, i3, 2.0f)
#undef TERM
        partials[chunk] = sum * (1.0f / 16.0f);
    }
}

// Deterministic final reduction of per-chunk partials; overwrites d_out[0].
__global__ __launch_bounds__(256) void reduce_kernel(
    const float* __restrict__ partials, float* __restrict__ out, int n)
{
    float s = 0.0f;
    for (int i = threadIdx.x * 4; i < n; i += 256 * 4) {
        const float4 v = *reinterpret_cast<const float4*>(partials + i);
        s += (v.x + v.y) + (v.z + v.w);
    }
#pragma unroll
    for (int d = 32; d > 0; d >>= 1) s += __shfl_xor(s, d, 64);
    __shared__ float lds[4];
    const int wave = threadIdx.x >> 6, lane = threadIdx.x & 63;
    if (lane == 0) lds[wave] = s;
    __syncthreads();
    if (threadIdx.x == 0) out[0] = lds[0] + lds[1] + lds[2] + lds[3];
}

extern "C" void kernel_launch(void* const* d_in, const int* in_sizes, int n_in,
                              void* d_out, int out_size, void* d_ws, size_t ws_size,
                              hipStream_t stream)
{
    const float* x = (const float*)d_in[0];
    float* out = (float*)d_out;
    float* partials = (float*)d_ws;   // C floats (16 KiB here)

    const int total  = in_sizes[0];
    const int C      = total / (NVIEWS * DIM);   // 4096 chunks
    const int blocks = (C + 1) / 2;              // 2 chunks per block

    chunk_loss_kernel<<<blocks, 256, 0, stream>>>(x, partials, C);
    reduce_kernel<<<1, 256, 0, stream>>>(partials, out, C);
}